// Round 4
// baseline (344.269 us; speedup 1.0000x reference)
//
#include <hip/hip_runtime.h>
#include <stdint.h>

// ---------------------------------------------------------------------------
// Fused LocalBranch: ResNetMLP (5x GEMM+LN) + per-graph distance softmax pool.
// One workgroup (512 thr = 8 waves) per graph; activations live in LDS (bf16).
// R4: B-matrix (weights) no longer staged through LDS — prep kernel packs
//     bf16 weights in MFMA-fragment order so each B-frag is one coalesced
//     1KB global_load_dwordx4 from L2 (weights are shared by all blocks and
//     L2-resident). LDS drops 160.7KB -> 73.2KB => 2 blocks/CU; barriers
//     ~25 -> ~15. waves_per_eu(4) pins regs <=128 for the 16-wave occupancy.
// ---------------------------------------------------------------------------

typedef __attribute__((ext_vector_type(8))) short bf16x8;   // 8 bf16 = 4 VGPRs
typedef __attribute__((ext_vector_type(4))) float f32x4;

#define XB_STRIDE 264            // 256 + 8 bf16 pad; A-frag reads land conflict-free
#define LDS_STATS 67584
#define LDS_STATQ 69632
#define LDS_SQV   71680
#define LDS_SM    72192
#define LDS_SMW   72704
#define LDS_TOTAL 73216          // 2 blocks/CU (2*73216 <= 163840)

__device__ __forceinline__ unsigned short f2bf(float f) {
  unsigned int u = __builtin_bit_cast(unsigned int, f);
  u += 0x7fffu + ((u >> 16) & 1u);           // RNE
  return (unsigned short)(u >> 16);
}
__device__ __forceinline__ float bf2f(unsigned short h) {
  unsigned int u = ((unsigned int)h) << 16;
  return __builtin_bit_cast(float, u);
}
__device__ __forceinline__ f32x4 zero4() {
  f32x4 v; v.x = 0.f; v.y = 0.f; v.z = 0.f; v.w = 0.f; return v;
}

// ---------------------------------------------------------------------------
// Weight prep: fp32 row-major W[K][N] -> bf16 MFMA-fragment order:
//   frag f = kc*(N/16) + ntile  (kc = 32-wide K slab), 64 lanes x 8 elems:
//   lane reads B[n = ntile*16 + (lane&15)][k = kc*32 + (lane>>4)*8 + e].
// ws regions (bf16 elems): stem @0 (16384) ; blocks @16384,81920,147456
// (65536 each) ; head @212992 (32768). dst is linear: ws + gid*8.
// ---------------------------------------------------------------------------
__global__ void prep_weights(const float* __restrict__ Win, const float* __restrict__ Wb,
                             const float* __restrict__ Wout, unsigned short* __restrict__ ws) {
  int g = blockIdx.x * 256 + threadIdx.x;     // one 8-elem lane-slot per thread
  if (g >= 30720) return;
  const float* W; int N; int local;
  if (g < 2048) { W = Win; N = 256; local = g; }
  else if (g < 26624) {
    int i = g - 2048; int blk = i >> 13; local = i & 8191;
    W = Wb + blk * 65536; N = 256;
  } else { W = Wout; N = 128; local = g - 26624; }
  int f = local >> 6, lane = local & 63;
  int NTL = N >> 4;
  int kc = f / NTL, ntile = f - kc * NTL;
  int n = ntile * 16 + (lane & 15);
  int k0 = kc * 32 + (lane >> 4) * 8;
  unsigned short o[8];
#pragma unroll
  for (int e = 0; e < 8; ++e) o[e] = f2bf(W[(size_t)(k0 + e) * N + n]);
  *reinterpret_cast<uint4*>(ws + (size_t)g * 8) = *reinterpret_cast<uint4*>(o);
}

// ---------------------------------------------------------------------------
// One GEMM(+bias+LN+act+residual) layer. Wave tile = 64 rows x (NT*16) cols.
// A from LDS (Xb), B-frags directly from global (frag-packed, L2-resident).
// MODE: 0 stem x=relu(ln) ; 1 residual x=Xb+relu(ln) (bf16 carry) ; 2 head z=ln.
// ---------------------------------------------------------------------------
template <int KL, int NT, int MODE>
__device__ __forceinline__ void layer_gemm(char* smem, const unsigned short* __restrict__ Wf,
                                           int wave, int lane,
                                           const float* __restrict__ bias,
                                           const float* __restrict__ gam,
                                           const float* __restrict__ bet) {
  const int mr = wave >> 2;          // 0..1 : row-block of wave
  const int nc = wave & 3;           // 0..3 : col-block of wave
  const int q = lane >> 4;
  const int l16 = lane & 15;
  unsigned short* Xb = (unsigned short*)smem;
  float* statS = (float*)(smem + LDS_STATS);
  float* statQ = (float*)(smem + LDS_STATQ);
  constexpr int C = KL / 64;         // 64-wide K chunks (2 MFMA k-steps each)
  constexpr int NTL = NT * 4;        // 16-col tiles across full N
  constexpr int NCOLS = NT * 64;
  const int colbase = nc * (NT * 16);
  const unsigned short* Wl = Wf + lane * 8;

  f32x4 acc[4][NT];
#pragma unroll
  for (int mt = 0; mt < 4; ++mt)
#pragma unroll
    for (int nt = 0; nt < NT; ++nt) acc[mt][nt] = zero4();

  __syncthreads();                   // Xb from previous layer ready
  for (int c = 0; c < C; ++c) {
#pragma unroll
    for (int ks = 0; ks < 2; ++ks) {
      const int kc = c * 2 + ks;
      bf16x8 b[NT], a[4];
#pragma unroll
      for (int nt = 0; nt < NT; ++nt)    // global B-frags first (long latency)
        b[nt] = *reinterpret_cast<const bf16x8*>(Wl + (size_t)(kc * NTL + nc * NT + nt) * 512);
      const int kk = kc * 32 + q * 8;
#pragma unroll
      for (int mt = 0; mt < 4; ++mt)
        a[mt] = *reinterpret_cast<const bf16x8*>(Xb + (64 * mr + 16 * mt + l16) * XB_STRIDE + kk);
#pragma unroll
      for (int mt = 0; mt < 4; ++mt)
#pragma unroll
        for (int nt = 0; nt < NT; ++nt)
          acc[mt][nt] = __builtin_amdgcn_mfma_f32_16x16x32_bf16(a[mt], b[nt], acc[mt][nt], 0, 0, 0);
    }
  }
  // ---- epilogue: bias, cross-wave LN stats, normalize, act, residual, store
  float bcol[NT], gcol[NT], becol[NT];
#pragma unroll
  for (int nt = 0; nt < NT; ++nt) {
    int col = colbase + 16 * nt + l16;
    bcol[nt] = bias[col]; gcol[nt] = gam[col]; becol[nt] = bet[col];
  }
#pragma unroll
  for (int mt = 0; mt < 4; ++mt) {
#pragma unroll
    for (int nt = 0; nt < NT; ++nt) {
      acc[mt][nt].x += bcol[nt]; acc[mt][nt].y += bcol[nt];
      acc[mt][nt].z += bcol[nt]; acc[mt][nt].w += bcol[nt];
    }
    f32x4 s1 = acc[mt][0];
    f32x4 s2 = acc[mt][0] * acc[mt][0];
#pragma unroll
    for (int nt = 1; nt < NT; ++nt) { s1 += acc[mt][nt]; s2 += acc[mt][nt] * acc[mt][nt]; }
#pragma unroll
    for (int d = 1; d < 16; d <<= 1) {
#pragma unroll
      for (int r = 0; r < 4; ++r) {
        float t1 = s1[r]; t1 += __shfl_xor(t1, d); s1[r] = t1;
        float t2 = s2[r]; t2 += __shfl_xor(t2, d); s2[r] = t2;
      }
    }
    if (l16 == 0) {
#pragma unroll
      for (int r = 0; r < 4; ++r) {
        int row = 64 * mr + 16 * mt + q * 4 + r;
        statS[row * 4 + nc] = s1[r];
        statQ[row * 4 + nc] = s2[r];
      }
    }
  }
  __syncthreads();                   // stats published; all A-reads of old Xb done
#pragma unroll
  for (int mt = 0; mt < 4; ++mt) {
#pragma unroll
    for (int r = 0; r < 4; ++r) {
      int row = 64 * mr + 16 * mt + q * 4 + r;
      float S1 = statS[row * 4 + 0] + statS[row * 4 + 1] + statS[row * 4 + 2] + statS[row * 4 + 3];
      float S2 = statQ[row * 4 + 0] + statQ[row * 4 + 1] + statQ[row * 4 + 2] + statQ[row * 4 + 3];
      float mu = S1 * (1.0f / NCOLS);
      float var = S2 * (1.0f / NCOLS) - mu * mu;
      float rstd = rsqrtf(var + 1e-5f);
#pragma unroll
      for (int nt = 0; nt < NT; ++nt) {
        int col = colbase + 16 * nt + l16;
        float y = (acc[mt][nt][r] - mu) * rstd * gcol[nt] + becol[nt];
        float xv;
        if constexpr (MODE == 0) { xv = fmaxf(y, 0.f); }
        else if constexpr (MODE == 1) {
          // residual base = this thread's own previous bf16 activation
          xv = bf2f(Xb[row * XB_STRIDE + col]) + fmaxf(y, 0.f);
        } else { xv = y; }
        Xb[row * XB_STRIDE + col] = f2bf(xv);
      }
    }
  }
}

// ---------------------------------------------------------------------------
__global__ __attribute__((amdgpu_flat_work_group_size(512, 512), amdgpu_waves_per_eu(4)))
void fused_main(
    const float* __restrict__ H, const unsigned short* __restrict__ ws,
    const float* __restrict__ b_in, const float* __restrict__ g_in, const float* __restrict__ beta_in,
    const float* __restrict__ bb, const float* __restrict__ gb, const float* __restrict__ betab,
    const float* __restrict__ b_out, const float* __restrict__ g_out, const float* __restrict__ beta_out,
    float* __restrict__ out) {
  extern __shared__ char smem[];
  const int tid = threadIdx.x;
  const int gidx = blockIdx.x;
  const int wave = tid >> 6;
  const int lane = tid & 63;
  const int q = lane >> 4;
  const int l16 = lane & 15;
  unsigned short* Xb = (unsigned short*)smem;
  float* sqv = (float*)(smem + LDS_SQV);
  float* sm  = (float*)(smem + LDS_SM);
  float* smw = (float*)(smem + LDS_SMW);

  // stage H tile (128x64) -> Xb as bf16 (packed b64 stores)
  {
    int row = tid >> 2, cb0 = (tid & 3) * 16;
    const float4* hp = reinterpret_cast<const float4*>(H + (size_t)(gidx * 128 + row) * 64 + cb0);
#pragma unroll
    for (int v4 = 0; v4 < 4; ++v4) {
      float4 f = hp[v4];
      ushort4 o; o.x = f2bf(f.x); o.y = f2bf(f.y); o.z = f2bf(f.z); o.w = f2bf(f.w);
      *reinterpret_cast<ushort4*>(Xb + row * XB_STRIDE + cb0 + v4 * 4) = o;
    }
  }

  layer_gemm<64, 4, 0>(smem, ws,           wave, lane, b_in,     g_in,     beta_in);
  layer_gemm<256, 4, 1>(smem, ws + 16384,  wave, lane, bb,       gb,       betab);
  layer_gemm<256, 4, 1>(smem, ws + 81920,  wave, lane, bb + 256, gb + 256, betab + 256);
  layer_gemm<256, 4, 1>(smem, ws + 147456, wave, lane, bb + 512, gb + 512, betab + 512);
  layer_gemm<256, 2, 2>(smem, ws + 212992, wave, lane, b_out,    g_out,    beta_out);
  __syncthreads();                       // Z (bf16, Xb cols 0..127) ready for all waves

  // ---- gram G = Z Z^T : wave owns 16 rows x 128 cols
  f32x4 g2[8];
#pragma unroll
  for (int nt = 0; nt < 8; ++nt) g2[nt] = zero4();
#pragma unroll
  for (int ks = 0; ks < 4; ++ks) {
    int kk = ks * 32 + q * 8;
    bf16x8 a = *reinterpret_cast<const bf16x8*>(Xb + (16 * wave + l16) * XB_STRIDE + kk);
#pragma unroll
    for (int nt = 0; nt < 8; ++nt) {
      bf16x8 bfr = *reinterpret_cast<const bf16x8*>(Xb + (16 * nt + l16) * XB_STRIDE + kk);
      g2[nt] = __builtin_amdgcn_mfma_f32_16x16x32_bf16(a, bfr, g2[nt], 0, 0, 0);
    }
  }
  // publish sq_i = G_ii (diag) so that d_ii == sqrt(1e-12) exactly like ref
  if ((l16 >> 2) == q) {
#pragma unroll
    for (int nt = 0; nt < 8; ++nt)
      if (nt == wave) {
#pragma unroll
        for (int r = 0; r < 4; ++r)
          if ((l16 & 3) == r) sqv[16 * wave + l16] = g2[nt][r];
      }
  }
  __syncthreads();
  // ---- distances and s_i = mean_j d_ij
  float sqi[4];
#pragma unroll
  for (int r = 0; r < 4; ++r) sqi[r] = sqv[16 * wave + q * 4 + r];
  float sp[4] = {0.f, 0.f, 0.f, 0.f};
#pragma unroll
  for (int nt = 0; nt < 8; ++nt) {
    float sqj = sqv[16 * nt + l16];
#pragma unroll
    for (int r = 0; r < 4; ++r) {
      float d2 = sqi[r] + sqj - 2.0f * g2[nt][r];
      sp[r] += sqrtf(fmaxf(d2, 0.f) + 1e-12f);
    }
  }
#pragma unroll
  for (int d = 1; d < 16; d <<= 1) {
#pragma unroll
    for (int r = 0; r < 4; ++r) { float t = sp[r]; t += __shfl_xor(t, d); sp[r] = t; }
  }
  if (l16 == 0) {
#pragma unroll
    for (int r = 0; r < 4; ++r) sm[16 * wave + q * 4 + r] = sp[r] * (1.0f / 128.0f);
  }
  __syncthreads();
  // ---- softmax(s/TAU) by wave 0 (1/TAU = 4)
  if (wave == 0) {
    float l0 = sm[lane] * 4.0f;
    float l1 = sm[lane + 64] * 4.0f;
    float mx = fmaxf(l0, l1);
#pragma unroll
    for (int d = 1; d < 64; d <<= 1) mx = fmaxf(mx, __shfl_xor(mx, d));
    float e0 = __expf(l0 - mx), e1 = __expf(l1 - mx);
    float ss = e0 + e1;
#pragma unroll
    for (int d = 1; d < 64; d <<= 1) ss += __shfl_xor(ss, d);
    float inv = 1.0f / ss;
    float w0 = e0 * inv, w1 = e1 * inv;
    smw[lane] = w0;
    smw[lane + 64] = w1;
    out[131072 + gidx * 128 + lane] = w0;
    out[131072 + gidx * 128 + 64 + lane] = w1;
  }
  __syncthreads();
  // ---- v_loc = sum_i w_i * Z[i,:] ; wave covers 16 cols, lanes split rows by q
  {
    int c = 16 * wave + l16;
    float acv = 0.f;
#pragma unroll
    for (int i0 = 0; i0 < 32; ++i0) {
      int i = q * 32 + i0;
      acv += smw[i] * bf2f(Xb[i * XB_STRIDE + c]);
    }
    acv += __shfl_xor(acv, 16);
    acv += __shfl_xor(acv, 32);
    if (q == 0) out[gidx * 128 + c] = acv;
  }
}

// ---------------------------------------------------------------------------
extern "C" void kernel_launch(void* const* d_in, const int* in_sizes, int n_in,
                              void* d_out, int out_size, void* d_ws, size_t ws_size,
                              hipStream_t stream) {
  (void)in_sizes; (void)n_in; (void)out_size; (void)ws_size;
  const float* H        = (const float*)d_in[0];
  // d_in[1] = batch_ptr (uniform 128/graph, unused)
  const float* W_in     = (const float*)d_in[2];
  const float* b_in     = (const float*)d_in[3];
  const float* g_in     = (const float*)d_in[4];
  const float* beta_in  = (const float*)d_in[5];
  const float* Wb       = (const float*)d_in[6];
  const float* bb       = (const float*)d_in[7];
  const float* gb       = (const float*)d_in[8];
  const float* betab    = (const float*)d_in[9];
  const float* W_out    = (const float*)d_in[10];
  const float* b_out    = (const float*)d_in[11];
  const float* g_out    = (const float*)d_in[12];
  const float* beta_out = (const float*)d_in[13];
  float* out = (float*)d_out;
  unsigned short* ws = (unsigned short*)d_ws;

  // re-create frag-packed bf16 weights every call (ws is re-poisoned each launch)
  prep_weights<<<120, 256, 0, stream>>>(W_in, Wb, W_out, ws);

  hipFuncSetAttribute(reinterpret_cast<const void*>(fused_main),
                      hipFuncAttributeMaxDynamicSharedMemorySize, LDS_TOTAL);
  fused_main<<<1024, 512, LDS_TOTAL, stream>>>(H, ws, b_in, g_in, beta_in,
                                               bb, gb, betab, b_out, g_out, beta_out, out);
}